// Round 1
// baseline (161.507 us; speedup 1.0000x reference)
//
#include <hip/hip_runtime.h>
#include <hip/hip_fp16.h>

#define CC 256   // input channels
#define OO 256   // output channels
#define HH 64
#define WW 64
#define HWN 4096 // H*W
#define MPB 32   // pixels per block
#define NPB 128  // outputs per block
#define VST 264  // val_lds row stride (halfs)

typedef _Float16 half8 __attribute__((ext_vector_type(8)));
typedef _Float16 half2v __attribute__((ext_vector_type(2)));
typedef float f32x4 __attribute__((ext_vector_type(4)));

__device__ __forceinline__ half2v u2h(unsigned u) {
  half2v h; __builtin_memcpy(&h, &u, 4); return h;
}
__device__ __forceinline__ unsigned h2u(half2v h) {
  unsigned u; __builtin_memcpy(&u, &h, 4); return u;
}
__device__ __forceinline__ unsigned short f2h(float f) {
  _Float16 h = (_Float16)f;
  unsigned short us; __builtin_memcpy(&us, &h, 2);
  return us;
}
__device__ __forceinline__ unsigned dupu(unsigned short us) {
  return ((unsigned)us << 16) | us;
}
__device__ __forceinline__ unsigned pk2(float a, float b) {
  half2v h = {(_Float16)a, (_Float16)b};
  return h2u(h);
}

// ---------- fused prep: x [N,C,H,W] f32 -> xt [N,HW,C] fp16 ; w -> wt [9][O][C] fp16 ----------
// LDS tile is [hw][c]; transpose happens on the WRITE side with scalar b32 stores
// (aligned, 2-way banks) instead of misaligned float4 stores at odd row stride.
__global__ __launch_bounds__(256) void prep_kernel(
    const float* __restrict__ x, const float* __restrict__ w,
    _Float16* __restrict__ xt, _Float16* __restrict__ wt) {
  __shared__ float tile[64][65];   // [hw][c], stride 65 f32: all scalar ops 2-way
  const int bid = blockIdx.x;
  const int tid = threadIdx.x;
  if (bid < 1024) {
    const int n  = bid >> 8;
    const int c0 = ((bid >> 6) & 3) * 64;
    const int s0 = (bid & 63) * 64;
    {
      int r  = tid >> 2;          // channel row 0..63
      int sc = (tid & 3) * 16;    // hw start
      const float* xp = x + ((size_t)(n * CC + c0 + r)) * HWN + s0 + sc;
      float4 va = *(const float4*)(xp);
      float4 vb = *(const float4*)(xp + 4);
      float4 vc = *(const float4*)(xp + 8);
      float4 vd = *(const float4*)(xp + 12);
      tile[sc + 0][r]  = va.x;  tile[sc + 1][r]  = va.y;
      tile[sc + 2][r]  = va.z;  tile[sc + 3][r]  = va.w;
      tile[sc + 4][r]  = vb.x;  tile[sc + 5][r]  = vb.y;
      tile[sc + 6][r]  = vb.z;  tile[sc + 7][r]  = vb.w;
      tile[sc + 8][r]  = vc.x;  tile[sc + 9][r]  = vc.y;
      tile[sc + 10][r] = vc.z;  tile[sc + 11][r] = vc.w;
      tile[sc + 12][r] = vd.x;  tile[sc + 13][r] = vd.y;
      tile[sc + 14][r] = vd.z;  tile[sc + 15][r] = vd.w;
    }
    __syncthreads();
    {
      int s  = tid >> 2;          // hw row
      int cg = (tid & 3) * 16;    // c start
      uint4 u0, u1;
      u0.x = pk2(tile[s][cg + 0],  tile[s][cg + 1]);
      u0.y = pk2(tile[s][cg + 2],  tile[s][cg + 3]);
      u0.z = pk2(tile[s][cg + 4],  tile[s][cg + 5]);
      u0.w = pk2(tile[s][cg + 6],  tile[s][cg + 7]);
      u1.x = pk2(tile[s][cg + 8],  tile[s][cg + 9]);
      u1.y = pk2(tile[s][cg + 10], tile[s][cg + 11]);
      u1.z = pk2(tile[s][cg + 12], tile[s][cg + 13]);
      u1.w = pk2(tile[s][cg + 14], tile[s][cg + 15]);
      _Float16* op = xt + ((size_t)(n * HWN + s0 + s)) * CC + c0 + cg;
      *(uint4*)(op)     = u0;
      *(uint4*)(op + 8) = u1;
    }
  } else {
    int e = (bid - 1024) * 256 + tid;   // 0 .. 589823
    int k = e >> 16;
    int o = (e >> 8) & 255;
    int c = e & 255;
    wt[e] = (_Float16)w[((size_t)o * CC + c) * 9 + k];
  }
}

// ---------------- fused deform-sample (fp16 packed) + MFMA GEMM ----------------
// grid 1024 x 256 thr. Block: 32 px x 128 o.
// B fragments are read DIRECTLY from wt (L2-resident, 1.18 MB) — no LDS staging
// (old w_lds had reuse factor 1: pure overhead + 4-way bank conflicts + 36 barriers).
// XCD-aware decode (XCD ~ bx%8): each XCD works on ONE image n, one o-half
//   nb = (bx&7)>>1, o-half = bx&1, pixel group = bx>>3 (0..127)
// -> per-XCD L2 working set = 2.1 MB xt slice + 0.59 MB wt half < 4 MiB.
__global__ __launch_bounds__(256, 4) void deform_mfma_kernel(
    const _Float16* __restrict__ xt,   // [4][4096][256] fp16
    const _Float16* __restrict__ wt,   // [9][256][256] fp16 ([k][o][c])
    const float* __restrict__ off,
    float* __restrict__ out) {
  __shared__ __align__(16) _Float16 val_lds[MPB * VST];   // 16896 B [p][c]
  __shared__ ushort4 s_po[MPB * 9];   // clamped flat corner row offsets (4608 B)
  __shared__ ushort4 s_pw[MPB * 9];   // fp16 bilinear weights (4608 B)

  const int tid  = threadIdx.x;
  const int lane = tid & 63;
  const int wv   = tid >> 6;
  const int n15  = lane & 15;
  const int quad = lane >> 4;

  const int bx    = blockIdx.x;
  const int nb    = (bx & 7) >> 1;          // image: constant per XCD
  const int hw0   = (bx >> 3) * MPB;        // pixel group within image
  const int obase = (bx & 1) * NPB;         // output half

  // ---- precompute per-(pixel,tap) sampling params ----
  for (int e = tid; e < MPB * 9; e += 256) {
    int p = e / 9;
    int k = e - p * 9;
    int hw = hw0 + p;
    int h = hw >> 6, w = hw & 63;
    size_t ob = ((size_t)(nb * HWN + hw)) * 18 + 2 * k;
    float2 d = *(const float2*)(off + ob);
    float py = (float)(h + k / 3 - 1) + d.x;
    float px = (float)(w + k % 3 - 1) + d.y;
    float fy = floorf(py), fx = floorf(px);
    int iy = (int)fy, ix = (int)fx;
    float wy = py - fy, wx = px - fx;
    float my0 = ((unsigned)iy       < (unsigned)HH) ? 1.f : 0.f;
    float my1 = ((unsigned)(iy + 1) < (unsigned)HH) ? 1.f : 0.f;
    float mx0 = ((unsigned)ix       < (unsigned)WW) ? 1.f : 0.f;
    float mx1 = ((unsigned)(ix + 1) < (unsigned)WW) ? 1.f : 0.f;
    int iy0 = min(max(iy, 0), HH - 1), iy1 = min(max(iy + 1, 0), HH - 1);
    int ix0 = min(max(ix, 0), WW - 1), ix1 = min(max(ix + 1, 0), WW - 1);
    s_po[e] = make_ushort4((unsigned short)(iy0 * WW + ix0),
                           (unsigned short)(iy0 * WW + ix1),
                           (unsigned short)(iy1 * WW + ix0),
                           (unsigned short)(iy1 * WW + ix1));
    s_pw[e] = make_ushort4(f2h((1.f - wy) * (1.f - wx) * my0 * mx0),
                           f2h((1.f - wy) * wx         * my0 * mx1),
                           f2h(wy         * (1.f - wx) * my1 * mx0),
                           f2h(wy         * wx         * my1 * mx1));
  }

  f32x4 acc[2][2];
#pragma unroll
  for (int a = 0; a < 2; ++a)
#pragma unroll
    for (int b = 0; b < 2; ++b) acc[a][b] = (f32x4){0.f, 0.f, 0.f, 0.f};

  const _Float16* xb = xt + (size_t)nb * HWN * CC;
  const int j = lane & 31;            // channel chunk j*8..j*8+7
  const int ph = lane >> 5;           // which pixel of the pair

  for (int k = 0; k < 9; ++k) {
    __syncthreads();   // prev tap A-reads done; (k==0) params visible

    // ---- sample tap k: 2 pixels per wave-iter, contiguous 512B row loads ----
#pragma unroll
    for (int i = 0; i < 4; ++i) {
      int p = i * 8 + wv * 2 + ph;
      int idx = p * 9 + k;
      ushort4 o4 = s_po[idx];
      ushort4 hw4 = s_pw[idx];
      half2v w00 = u2h(dupu(hw4.x)), w01 = u2h(dupu(hw4.y));
      half2v w10 = u2h(dupu(hw4.z)), w11 = u2h(dupu(hw4.w));
      const _Float16* cb = xb + (size_t)j * 8;
      uint4 v00 = *(const uint4*)(cb + (size_t)o4.x * CC);
      uint4 v01 = *(const uint4*)(cb + (size_t)o4.y * CC);
      uint4 v10 = *(const uint4*)(cb + (size_t)o4.z * CC);
      uint4 v11 = *(const uint4*)(cb + (size_t)o4.w * CC);
      uint4 r;
      r.x = h2u(u2h(v00.x) * w00 + u2h(v01.x) * w01 + u2h(v10.x) * w10 + u2h(v11.x) * w11);
      r.y = h2u(u2h(v00.y) * w00 + u2h(v01.y) * w01 + u2h(v10.y) * w10 + u2h(v11.y) * w11);
      r.z = h2u(u2h(v00.z) * w00 + u2h(v01.z) * w01 + u2h(v10.z) * w10 + u2h(v11.z) * w11);
      r.w = h2u(u2h(v00.w) * w00 + u2h(v01.w) * w01 + u2h(v10.w) * w10 + u2h(v11.w) * w11);
      *(uint4*)(val_lds + p * VST + j * 8) = r;   // consecutive 16B per half-wave
    }
    __syncthreads();   // val_lds staged for tap k

    // ---- GEMM tap k: A from LDS, B straight from L2 ----
    const _Float16* wb = wt + ((size_t)(k * OO + obase + wv * 32)) * CC;
#pragma unroll
    for (int ks = 0; ks < 8; ++ks) {
      half8 afr[2], bfr[2];
#pragma unroll
      for (int mt = 0; mt < 2; ++mt)
        afr[mt] = *(const half8*)(val_lds + (mt * 16 + n15) * VST + ks * 32 + quad * 8);
#pragma unroll
      for (int nt = 0; nt < 2; ++nt)
        bfr[nt] = *(const half8*)(wb + (size_t)(nt * 16 + n15) * CC + ks * 32 + quad * 8);
#pragma unroll
      for (int mt = 0; mt < 2; ++mt)
#pragma unroll
        for (int nt = 0; nt < 2; ++nt)
          acc[mt][nt] = __builtin_amdgcn_mfma_f32_16x16x32_f16(
              afr[mt], bfr[nt], acc[mt][nt], 0, 0, 0);
    }
  }

  // ---- epilogue: D: col=lane&15 -> o, row=quad*4+reg -> pixel ----
#pragma unroll
  for (int mt = 0; mt < 2; ++mt)
#pragma unroll
    for (int nt = 0; nt < 2; ++nt) {
      int o  = obase + wv * 32 + nt * 16 + n15;
      int px = hw0 + mt * 16 + quad * 4;
      *(f32x4*)(out + ((size_t)nb * OO + o) * HWN + px) = acc[mt][nt];
    }
}

extern "C" void kernel_launch(void* const* d_in, const int* in_sizes, int n_in,
                              void* d_out, int out_size, void* d_ws, size_t ws_size,
                              hipStream_t stream) {
  const float* x   = (const float*)d_in[0];   // [4,256,64,64]
  const float* off = (const float*)d_in[1];   // [4,4096,18]
  const float* w   = (const float*)d_in[2];   // [256,256,3,3]
  float* out = (float*)d_out;                 // [4,256,64,64]

  _Float16* wt = (_Float16*)d_ws;             // 589824 fp16
  _Float16* xt = wt + 589824;                 // 4194304 fp16

  prep_kernel<<<1024 + 2304, 256, 0, stream>>>(x, w, xt, wt);
  deform_mfma_kernel<<<(4 * HWN / MPB) * (OO / NPB), 256, 0, stream>>>(xt, wt, off, out);
}

// Round 2
// 137.398 us; speedup vs baseline: 1.1755x; 1.1755x over previous
//
#include <hip/hip_runtime.h>
#include <hip/hip_fp16.h>

#define CC 256   // input channels
#define OO 256   // output channels
#define HH 64
#define WW 64
#define HWN 4096 // H*W
#define MPB 64   // pixels per block
#define NPB 128  // outputs per block
#define VST 264  // val_lds row stride (halfs)

typedef _Float16 half8 __attribute__((ext_vector_type(8)));
typedef _Float16 half2v __attribute__((ext_vector_type(2)));
typedef float f32x4 __attribute__((ext_vector_type(4)));

__device__ __forceinline__ half2v u2h(unsigned u) {
  half2v h; __builtin_memcpy(&h, &u, 4); return h;
}
__device__ __forceinline__ unsigned h2u(half2v h) {
  unsigned u; __builtin_memcpy(&u, &h, 4); return u;
}
__device__ __forceinline__ unsigned short f2h(float f) {
  _Float16 h = (_Float16)f;
  unsigned short us; __builtin_memcpy(&us, &h, 2);
  return us;
}
__device__ __forceinline__ unsigned dupu(unsigned short us) {
  return ((unsigned)us << 16) | us;
}
__device__ __forceinline__ unsigned pk2(float a, float b) {
  half2v h = {(_Float16)a, (_Float16)b};
  return h2u(h);
}

// ---------- fused prep ----------
// blocks 0..1023:  x [N,C,H,W] f32 -> xt [N,HW,C] fp16   (64c x 64hw tile via LDS)
// blocks 1024..1279: w [O,C,3,3] f32 -> wt [9][O][C] fp16 (one block per o;
//   contiguous 9216B read, LDS transpose, coalesced 512B-row writes)
__global__ __launch_bounds__(256) void prep_kernel(
    const float* __restrict__ x, const float* __restrict__ w,
    _Float16* __restrict__ xt, _Float16* __restrict__ wt) {
  const int bid = blockIdx.x;
  const int tid = threadIdx.x;
  if (bid < 1024) {
    __shared__ float tile[64][65];   // [hw][c]
    const int n  = bid >> 8;
    const int c0 = ((bid >> 6) & 3) * 64;
    const int s0 = (bid & 63) * 64;
    {
      int r  = tid >> 2;          // channel row 0..63
      int sc = (tid & 3) * 16;    // hw start
      const float* xp = x + ((size_t)(n * CC + c0 + r)) * HWN + s0 + sc;
      float4 va = *(const float4*)(xp);
      float4 vb = *(const float4*)(xp + 4);
      float4 vc = *(const float4*)(xp + 8);
      float4 vd = *(const float4*)(xp + 12);
      tile[sc + 0][r]  = va.x;  tile[sc + 1][r]  = va.y;
      tile[sc + 2][r]  = va.z;  tile[sc + 3][r]  = va.w;
      tile[sc + 4][r]  = vb.x;  tile[sc + 5][r]  = vb.y;
      tile[sc + 6][r]  = vb.z;  tile[sc + 7][r]  = vb.w;
      tile[sc + 8][r]  = vc.x;  tile[sc + 9][r]  = vc.y;
      tile[sc + 10][r] = vc.z;  tile[sc + 11][r] = vc.w;
      tile[sc + 12][r] = vd.x;  tile[sc + 13][r] = vd.y;
      tile[sc + 14][r] = vd.z;  tile[sc + 15][r] = vd.w;
    }
    __syncthreads();
    {
      int s  = tid >> 2;          // hw row
      int cg = (tid & 3) * 16;    // c start
      uint4 u0, u1;
      u0.x = pk2(tile[s][cg + 0],  tile[s][cg + 1]);
      u0.y = pk2(tile[s][cg + 2],  tile[s][cg + 3]);
      u0.z = pk2(tile[s][cg + 4],  tile[s][cg + 5]);
      u0.w = pk2(tile[s][cg + 6],  tile[s][cg + 7]);
      u1.x = pk2(tile[s][cg + 8],  tile[s][cg + 9]);
      u1.y = pk2(tile[s][cg + 10], tile[s][cg + 11]);
      u1.z = pk2(tile[s][cg + 12], tile[s][cg + 13]);
      u1.w = pk2(tile[s][cg + 14], tile[s][cg + 15]);
      _Float16* op = xt + ((size_t)(n * HWN + s0 + s)) * CC + c0 + cg;
      *(uint4*)(op)     = u0;
      *(uint4*)(op + 8) = u1;
    }
  } else {
    __shared__ _Float16 wrow[9][264];   // [k][c], 2-way banks on both phases
    const int o = bid - 1024;
    const float* wp = w + (size_t)o * (CC * 9);
    // thread c = tid reads its 9 consecutive floats (block region fully contiguous)
    float v[9];
#pragma unroll
    for (int k = 0; k < 9; ++k) v[k] = wp[tid * 9 + k];
#pragma unroll
    for (int k = 0; k < 9; ++k) wrow[k][tid] = (_Float16)v[k];
    __syncthreads();
    // 9 rows of 512B, each written by 64 lanes x 8B, fully coalesced
    for (int r = tid; r < 9 * 64; r += 256) {
      int k  = r >> 6;
      int c4 = (r & 63) * 4;
      *(uint2*)(wt + (size_t)k * (OO * CC) + (size_t)o * CC + c4) =
          *(const uint2*)(&wrow[k][c4]);
    }
  }
}

// ---------------- fused deform-sample (fp16 packed) + MFMA GEMM ----------------
// grid 512 x 256 thr. Block: 64 px x 128 o. 3 blocks/CU (LDS 43KB, regs<=170).
// Per tap: B fragments for the WHOLE tap (32 o-rows/wave, 16x b128 = 64 VGPR)
// are loaded from L2-resident wt at tap start; their latency hides under the
// sampling phase. No w_lds: 18 barriers/block instead of 45, no staging traffic.
// Weight L2 traffic: 512 blocks x 590KB = 302 MB (round-0 level).
// XCD-aware decode (XCD ~ bx%8): each XCD works on ONE image n, one o-half
//   nb = (bx&7)>>1, o-half = bx&1, pixel group = bx>>3
// -> per-XCD L2 working set = 2.1 MB xt slice + 0.59 MB wt half < 4 MiB.
__global__ __launch_bounds__(256, 3) void deform_mfma_kernel(
    const _Float16* __restrict__ xt,   // [4][4096][256] fp16
    const _Float16* __restrict__ wt,   // [9][256][256] fp16 ([k][o][c])
    const float* __restrict__ off,
    float* __restrict__ out) {
  __shared__ __align__(16) _Float16 val_lds[MPB * VST];   // 33792 B [p][c]
  __shared__ ushort4 s_po[MPB * 9];   // clamped flat corner row offsets (4608 B)
  __shared__ ushort4 s_pw[MPB * 9];   // fp16 bilinear weights (4608 B)

  const int tid  = threadIdx.x;
  const int lane = tid & 63;
  const int wv   = tid >> 6;
  const int n15  = lane & 15;
  const int quad = lane >> 4;

  const int bx    = blockIdx.x;
  const int nb    = (bx & 7) >> 1;          // image: constant per XCD
  const int hw0   = (bx >> 3) * MPB;        // pixel group within image
  const int obase = (bx & 1) * NPB;         // output half

  // ---- precompute per-(pixel,tap) sampling params ----
  for (int e = tid; e < MPB * 9; e += 256) {
    int p = e / 9;
    int k = e - p * 9;
    int hw = hw0 + p;
    int h = hw >> 6, w = hw & 63;
    size_t ob = ((size_t)(nb * HWN + hw)) * 18 + 2 * k;
    float2 d = *(const float2*)(off + ob);
    float py = (float)(h + k / 3 - 1) + d.x;
    float px = (float)(w + k % 3 - 1) + d.y;
    float fy = floorf(py), fx = floorf(px);
    int iy = (int)fy, ix = (int)fx;
    float wy = py - fy, wx = px - fx;
    float my0 = ((unsigned)iy       < (unsigned)HH) ? 1.f : 0.f;
    float my1 = ((unsigned)(iy + 1) < (unsigned)HH) ? 1.f : 0.f;
    float mx0 = ((unsigned)ix       < (unsigned)WW) ? 1.f : 0.f;
    float mx1 = ((unsigned)(ix + 1) < (unsigned)WW) ? 1.f : 0.f;
    int iy0 = min(max(iy, 0), HH - 1), iy1 = min(max(iy + 1, 0), HH - 1);
    int ix0 = min(max(ix, 0), WW - 1), ix1 = min(max(ix + 1, 0), WW - 1);
    s_po[e] = make_ushort4((unsigned short)(iy0 * WW + ix0),
                           (unsigned short)(iy0 * WW + ix1),
                           (unsigned short)(iy1 * WW + ix0),
                           (unsigned short)(iy1 * WW + ix1));
    s_pw[e] = make_ushort4(f2h((1.f - wy) * (1.f - wx) * my0 * mx0),
                           f2h((1.f - wy) * wx         * my0 * mx1),
                           f2h(wy         * (1.f - wx) * my1 * mx0),
                           f2h(wy         * wx         * my1 * mx1));
  }

  f32x4 acc[4][2];
#pragma unroll
  for (int a = 0; a < 4; ++a)
#pragma unroll
    for (int b = 0; b < 2; ++b) acc[a][b] = (f32x4){0.f, 0.f, 0.f, 0.f};

  const _Float16* xb = xt + (size_t)nb * HWN * CC;
  const int j = lane & 31;            // channel chunk j*8..j*8+7
  const int ph = lane >> 5;           // which pixel of the pair

  for (int k = 0; k < 9; ++k) {
    __syncthreads();   // prev tap A-reads done; (k==0) params visible

    // ---- issue this tap's B loads early: latency hides under sampling ----
    const _Float16* wb = wt + ((size_t)(k * OO + obase + wv * 32)) * CC;
    half8 bfr[8][2];
#pragma unroll
    for (int ks = 0; ks < 8; ++ks)
#pragma unroll
      for (int nt = 0; nt < 2; ++nt)
        bfr[ks][nt] = *(const half8*)(wb + (size_t)(nt * 16 + n15) * CC + ks * 32 + quad * 8);

    // ---- sample tap k: 2 pixels per wave-iter, contiguous 512B row loads ----
#pragma unroll
    for (int i = 0; i < 8; ++i) {
      int p = i * 8 + wv * 2 + ph;
      int idx = p * 9 + k;
      ushort4 o4 = s_po[idx];
      ushort4 hw4 = s_pw[idx];
      half2v w00 = u2h(dupu(hw4.x)), w01 = u2h(dupu(hw4.y));
      half2v w10 = u2h(dupu(hw4.z)), w11 = u2h(dupu(hw4.w));
      const _Float16* cb = xb + (size_t)j * 8;
      uint4 v00 = *(const uint4*)(cb + (size_t)o4.x * CC);
      uint4 v01 = *(const uint4*)(cb + (size_t)o4.y * CC);
      uint4 v10 = *(const uint4*)(cb + (size_t)o4.z * CC);
      uint4 v11 = *(const uint4*)(cb + (size_t)o4.w * CC);
      uint4 r;
      r.x = h2u(u2h(v00.x) * w00 + u2h(v01.x) * w01 + u2h(v10.x) * w10 + u2h(v11.x) * w11);
      r.y = h2u(u2h(v00.y) * w00 + u2h(v01.y) * w01 + u2h(v10.y) * w10 + u2h(v11.y) * w11);
      r.z = h2u(u2h(v00.z) * w00 + u2h(v01.z) * w01 + u2h(v10.z) * w10 + u2h(v11.z) * w11);
      r.w = h2u(u2h(v00.w) * w00 + u2h(v01.w) * w01 + u2h(v10.w) * w10 + u2h(v11.w) * w11);
      *(uint4*)(val_lds + p * VST + j * 8) = r;   // consecutive 16B per half-wave
    }
    __syncthreads();   // val_lds staged for tap k

    // ---- GEMM tap k: A from LDS, B already in registers ----
#pragma unroll
    for (int ks = 0; ks < 8; ++ks) {
      half8 afr[4];
#pragma unroll
      for (int mt = 0; mt < 4; ++mt)
        afr[mt] = *(const half8*)(val_lds + (mt * 16 + n15) * VST + ks * 32 + quad * 8);
#pragma unroll
      for (int mt = 0; mt < 4; ++mt)
#pragma unroll
        for (int nt = 0; nt < 2; ++nt)
          acc[mt][nt] = __builtin_amdgcn_mfma_f32_16x16x32_f16(
              afr[mt], bfr[ks][nt], acc[mt][nt], 0, 0, 0);
    }
  }

  // ---- epilogue: D: col=lane&15 -> o, row=quad*4+reg -> pixel ----
#pragma unroll
  for (int mt = 0; mt < 4; ++mt)
#pragma unroll
    for (int nt = 0; nt < 2; ++nt) {
      int o  = obase + wv * 32 + nt * 16 + n15;
      int px = hw0 + mt * 16 + quad * 4;
      *(f32x4*)(out + ((size_t)nb * OO + o) * HWN + px) = acc[mt][nt];
    }
}

extern "C" void kernel_launch(void* const* d_in, const int* in_sizes, int n_in,
                              void* d_out, int out_size, void* d_ws, size_t ws_size,
                              hipStream_t stream) {
  const float* x   = (const float*)d_in[0];   // [4,256,64,64]
  const float* off = (const float*)d_in[1];   // [4,4096,18]
  const float* w   = (const float*)d_in[2];   // [256,256,3,3]
  float* out = (float*)d_out;                 // [4,256,64,64]

  _Float16* wt = (_Float16*)d_ws;             // 589824 fp16
  _Float16* xt = wt + 589824;                 // 4194304 fp16

  prep_kernel<<<1024 + 256, 256, 0, stream>>>(x, w, xt, wt);
  deform_mfma_kernel<<<(4 * HWN / MPB) * (OO / NPB), 256, 0, stream>>>(xt, wt, off, out);
}

// Round 3
// 133.103 us; speedup vs baseline: 1.2134x; 1.0323x over previous
//
#include <hip/hip_runtime.h>
#include <hip/hip_fp16.h>

#define CC 256   // input channels
#define OO 256   // output channels
#define HH 64
#define WW 64
#define HWN 4096 // H*W
#define MPB 64   // pixels per block
#define NPB 128  // outputs per block
#define VST 264  // val_lds row stride (halfs)
#define VOFF (MPB * VST)   // halfs per val buffer

typedef _Float16 half8 __attribute__((ext_vector_type(8)));
typedef _Float16 half2v __attribute__((ext_vector_type(2)));
typedef float f32x4 __attribute__((ext_vector_type(4)));

__device__ __forceinline__ half2v u2h(unsigned u) {
  half2v h; __builtin_memcpy(&h, &u, 4); return h;
}
__device__ __forceinline__ unsigned h2u(half2v h) {
  unsigned u; __builtin_memcpy(&u, &h, 4); return u;
}
__device__ __forceinline__ unsigned short f2h(float f) {
  _Float16 h = (_Float16)f;
  unsigned short us; __builtin_memcpy(&us, &h, 2);
  return us;
}
__device__ __forceinline__ unsigned dupu(unsigned short us) {
  return ((unsigned)us << 16) | us;
}
__device__ __forceinline__ unsigned pk2(float a, float b) {
  half2v h = {(_Float16)a, (_Float16)b};
  return h2u(h);
}

// ---------- fused prep (UNCHANGED from round 2 — controlled experiment) ----------
// blocks 0..1023:  x [N,C,H,W] f32 -> xt [N,HW,C] fp16   (64c x 64hw tile via LDS)
// blocks 1024..1279: w [O,C,3,3] f32 -> wt [9][O][C] fp16
__global__ __launch_bounds__(256) void prep_kernel(
    const float* __restrict__ x, const float* __restrict__ w,
    _Float16* __restrict__ xt, _Float16* __restrict__ wt) {
  const int bid = blockIdx.x;
  const int tid = threadIdx.x;
  if (bid < 1024) {
    __shared__ float tile[64][65];   // [hw][c]
    const int n  = bid >> 8;
    const int c0 = ((bid >> 6) & 3) * 64;
    const int s0 = (bid & 63) * 64;
    {
      int r  = tid >> 2;          // channel row 0..63
      int sc = (tid & 3) * 16;    // hw start
      const float* xp = x + ((size_t)(n * CC + c0 + r)) * HWN + s0 + sc;
      float4 va = *(const float4*)(xp);
      float4 vb = *(const float4*)(xp + 4);
      float4 vc = *(const float4*)(xp + 8);
      float4 vd = *(const float4*)(xp + 12);
      tile[sc + 0][r]  = va.x;  tile[sc + 1][r]  = va.y;
      tile[sc + 2][r]  = va.z;  tile[sc + 3][r]  = va.w;
      tile[sc + 4][r]  = vb.x;  tile[sc + 5][r]  = vb.y;
      tile[sc + 6][r]  = vb.z;  tile[sc + 7][r]  = vb.w;
      tile[sc + 8][r]  = vc.x;  tile[sc + 9][r]  = vc.y;
      tile[sc + 10][r] = vc.z;  tile[sc + 11][r] = vc.w;
      tile[sc + 12][r] = vd.x;  tile[sc + 13][r] = vd.y;
      tile[sc + 14][r] = vd.z;  tile[sc + 15][r] = vd.w;
    }
    __syncthreads();
    {
      int s  = tid >> 2;          // hw row
      int cg = (tid & 3) * 16;    // c start
      uint4 u0, u1;
      u0.x = pk2(tile[s][cg + 0],  tile[s][cg + 1]);
      u0.y = pk2(tile[s][cg + 2],  tile[s][cg + 3]);
      u0.z = pk2(tile[s][cg + 4],  tile[s][cg + 5]);
      u0.w = pk2(tile[s][cg + 6],  tile[s][cg + 7]);
      u1.x = pk2(tile[s][cg + 8],  tile[s][cg + 9]);
      u1.y = pk2(tile[s][cg + 10], tile[s][cg + 11]);
      u1.z = pk2(tile[s][cg + 12], tile[s][cg + 13]);
      u1.w = pk2(tile[s][cg + 14], tile[s][cg + 15]);
      _Float16* op = xt + ((size_t)(n * HWN + s0 + s)) * CC + c0 + cg;
      *(uint4*)(op)     = u0;
      *(uint4*)(op + 8) = u1;
    }
  } else {
    __shared__ _Float16 wrow[9][264];
    const int o = bid - 1024;
    const float* wp = w + (size_t)o * (CC * 9);
    float v[9];
#pragma unroll
    for (int k = 0; k < 9; ++k) v[k] = wp[tid * 9 + k];
#pragma unroll
    for (int k = 0; k < 9; ++k) wrow[k][tid] = (_Float16)v[k];
    __syncthreads();
    for (int r = tid; r < 9 * 64; r += 256) {
      int k  = r >> 6;
      int c4 = (r & 63) * 4;
      *(uint2*)(wt + (size_t)k * (OO * CC) + (size_t)o * CC + c4) =
          *(const uint2*)(&wrow[k][c4]);
    }
  }
}

// ---------------- fused deform-sample + MFMA GEMM, double-buffered pipeline ----------------
// grid 512 x 256 thr. Block: 64 px x 128 o. 2 blocks/CU (LDS 75KB).
// ONE barrier per tap. Within tap k the source interleaves:
//   sample-iter(tap k+1 -> buf nxt)  ||  {A ds_read + 8 MFMA}(tap k <- buf cur)
// so the 32 scattered L2 sample loads + 16 B b128 loads hide under 64 MFMAs.
// XCD-aware decode: nb=(bx&7)>>1, o-half=bx&1, pixel group=bx>>3.
__global__ __launch_bounds__(256, 2) void deform_mfma_kernel(
    const _Float16* __restrict__ xt,   // [4][4096][256] fp16
    const _Float16* __restrict__ wt,   // [9][256][256] fp16 ([k][o][c])
    const float* __restrict__ off,
    float* __restrict__ out) {
  __shared__ __align__(16) _Float16 val_lds[2 * VOFF];   // 67584 B, [buf][p][c]
  __shared__ ushort4 s_po[MPB * 9];   // clamped flat corner row offsets (4608 B)
  __shared__ ushort4 s_pw[MPB * 9];   // fp16 bilinear weights (4608 B)

  const int tid  = threadIdx.x;
  const int lane = tid & 63;
  const int wv   = tid >> 6;
  const int n15  = lane & 15;
  const int quad = lane >> 4;

  const int bx    = blockIdx.x;
  const int nb    = (bx & 7) >> 1;          // image: constant per XCD
  const int hw0   = (bx >> 3) * MPB;        // pixel group within image
  const int obase = (bx & 1) * NPB;         // output half

  // ---- precompute per-(pixel,tap) sampling params ----
  for (int e = tid; e < MPB * 9; e += 256) {
    int p = e / 9;
    int k = e - p * 9;
    int hw = hw0 + p;
    int h = hw >> 6, w = hw & 63;
    size_t ob = ((size_t)(nb * HWN + hw)) * 18 + 2 * k;
    float2 d = *(const float2*)(off + ob);
    float py = (float)(h + k / 3 - 1) + d.x;
    float px = (float)(w + k % 3 - 1) + d.y;
    float fy = floorf(py), fx = floorf(px);
    int iy = (int)fy, ix = (int)fx;
    float wy = py - fy, wx = px - fx;
    float my0 = ((unsigned)iy       < (unsigned)HH) ? 1.f : 0.f;
    float my1 = ((unsigned)(iy + 1) < (unsigned)HH) ? 1.f : 0.f;
    float mx0 = ((unsigned)ix       < (unsigned)WW) ? 1.f : 0.f;
    float mx1 = ((unsigned)(ix + 1) < (unsigned)WW) ? 1.f : 0.f;
    int iy0 = min(max(iy, 0), HH - 1), iy1 = min(max(iy + 1, 0), HH - 1);
    int ix0 = min(max(ix, 0), WW - 1), ix1 = min(max(ix + 1, 0), WW - 1);
    s_po[e] = make_ushort4((unsigned short)(iy0 * WW + ix0),
                           (unsigned short)(iy0 * WW + ix1),
                           (unsigned short)(iy1 * WW + ix0),
                           (unsigned short)(iy1 * WW + ix1));
    s_pw[e] = make_ushort4(f2h((1.f - wy) * (1.f - wx) * my0 * mx0),
                           f2h((1.f - wy) * wx         * my0 * mx1),
                           f2h(wy         * (1.f - wx) * my1 * mx0),
                           f2h(wy         * wx         * my1 * mx1));
  }

  f32x4 acc[4][2];
#pragma unroll
  for (int a = 0; a < 4; ++a)
#pragma unroll
    for (int b = 0; b < 2; ++b) acc[a][b] = (f32x4){0.f, 0.f, 0.f, 0.f};

  const _Float16* xb = xt + (size_t)nb * HWN * CC;
  const int j = lane & 31;            // channel chunk j*8..j*8+7
  const int ph = lane >> 5;           // which pixel of the pair

  // one sampling iteration: pixel-pair i of tap kk -> buffer bb
  auto sample_iter = [&](int kk, int bb, int i) {
    int p = i * 8 + wv * 2 + ph;
    int idx = p * 9 + kk;
    ushort4 o4 = s_po[idx];
    ushort4 hw4 = s_pw[idx];
    half2v w00 = u2h(dupu(hw4.x)), w01 = u2h(dupu(hw4.y));
    half2v w10 = u2h(dupu(hw4.z)), w11 = u2h(dupu(hw4.w));
    const _Float16* cb = xb + (size_t)j * 8;
    uint4 v00 = *(const uint4*)(cb + (size_t)o4.x * CC);
    uint4 v01 = *(const uint4*)(cb + (size_t)o4.y * CC);
    uint4 v10 = *(const uint4*)(cb + (size_t)o4.z * CC);
    uint4 v11 = *(const uint4*)(cb + (size_t)o4.w * CC);
    uint4 r;
    r.x = h2u(u2h(v00.x) * w00 + u2h(v01.x) * w01 + u2h(v10.x) * w10 + u2h(v11.x) * w11);
    r.y = h2u(u2h(v00.y) * w00 + u2h(v01.y) * w01 + u2h(v10.y) * w10 + u2h(v11.y) * w11);
    r.z = h2u(u2h(v00.z) * w00 + u2h(v01.z) * w01 + u2h(v10.z) * w10 + u2h(v11.z) * w11);
    r.w = h2u(u2h(v00.w) * w00 + u2h(v01.w) * w01 + u2h(v10.w) * w10 + u2h(v11.w) * w11);
    *(uint4*)(val_lds + bb * VOFF + p * VST + j * 8) = r;
  };

  __syncthreads();           // params visible
  // prologue: sample tap 0 into buffer 0
#pragma unroll
  for (int i = 0; i < 8; ++i) sample_iter(0, 0, i);

  for (int k = 0; k < 8; ++k) {
    __syncthreads();   // buf[k&1] fully written; prev GEMM reads done
    const int cur = k & 1;
    const int nxt = cur ^ 1;
    const _Float16* wb = wt + ((size_t)(k * OO + obase + wv * 32)) * CC;
#pragma unroll
    for (int ks = 0; ks < 8; ++ks) {
      // prefetch-pipeline: next tap's sample iter goes first so its loads issue early
      sample_iter(k + 1, nxt, ks);
      half8 bfr[2];
#pragma unroll
      for (int nt = 0; nt < 2; ++nt)
        bfr[nt] = *(const half8*)(wb + (size_t)(nt * 16 + n15) * CC + ks * 32 + quad * 8);
      half8 afr[4];
#pragma unroll
      for (int mt = 0; mt < 4; ++mt)
        afr[mt] = *(const half8*)(val_lds + cur * VOFF + (mt * 16 + n15) * VST + ks * 32 + quad * 8);
#pragma unroll
      for (int mt = 0; mt < 4; ++mt)
#pragma unroll
        for (int nt = 0; nt < 2; ++nt)
          acc[mt][nt] = __builtin_amdgcn_mfma_f32_16x16x32_f16(
              afr[mt], bfr[nt], acc[mt][nt], 0, 0, 0);
    }
  }

  // tail: tap 8 GEMM (buffer 0), no further sampling
  __syncthreads();
  {
    const _Float16* wb = wt + ((size_t)(8 * OO + obase + wv * 32)) * CC;
#pragma unroll
    for (int ks = 0; ks < 8; ++ks) {
      half8 bfr[2];
#pragma unroll
      for (int nt = 0; nt < 2; ++nt)
        bfr[nt] = *(const half8*)(wb + (size_t)(nt * 16 + n15) * CC + ks * 32 + quad * 8);
      half8 afr[4];
#pragma unroll
      for (int mt = 0; mt < 4; ++mt)
        afr[mt] = *(const half8*)(val_lds + (mt * 16 + n15) * VST + ks * 32 + quad * 8);
#pragma unroll
      for (int mt = 0; mt < 4; ++mt)
#pragma unroll
        for (int nt = 0; nt < 2; ++nt)
          acc[mt][nt] = __builtin_amdgcn_mfma_f32_16x16x32_f16(
              afr[mt], bfr[nt], acc[mt][nt], 0, 0, 0);
    }
  }

  // ---- epilogue: D: col=lane&15 -> o, row=quad*4+reg -> pixel ----
#pragma unroll
  for (int mt = 0; mt < 4; ++mt)
#pragma unroll
    for (int nt = 0; nt < 2; ++nt) {
      int o  = obase + wv * 32 + nt * 16 + n15;
      int px = hw0 + mt * 16 + quad * 4;
      *(f32x4*)(out + ((size_t)nb * OO + o) * HWN + px) = acc[mt][nt];
    }
}

extern "C" void kernel_launch(void* const* d_in, const int* in_sizes, int n_in,
                              void* d_out, int out_size, void* d_ws, size_t ws_size,
                              hipStream_t stream) {
  const float* x   = (const float*)d_in[0];   // [4,256,64,64]
  const float* off = (const float*)d_in[1];   // [4,4096,18]
  const float* w   = (const float*)d_in[2];   // [256,256,3,3]
  float* out = (float*)d_out;                 // [4,256,64,64]

  _Float16* wt = (_Float16*)d_ws;             // 589824 fp16
  _Float16* xt = wt + 589824;                 // 4194304 fp16

  prep_kernel<<<1024 + 256, 256, 0, stream>>>(x, w, xt, wt);
  deform_mfma_kernel<<<(4 * HWN / MPB) * (OO / NPB), 256, 0, stream>>>(xt, wt, off, out);
}